// Round 5
// baseline (467.208 us; speedup 1.0000x reference)
//
#include <hip/hip_runtime.h>

// DiscriminativeLoss — B=8, D=32, N=131072, K=64 bins.
// R5 decomposition: R2-R4 falsified atomics/stride/bank-conflict theories;
// counters show ~9 cache lines in flight per CU (390 GB/s @ ~900cy) = MLP
// collapse. This round: (a) k5_ctl m13-shape pure-read control, (b) k1 at 8
// blocks/CU with explicit 2-stage load pipeline, (c) pass 2 split into
// streaming pd partials + plane-sum/hinge kernel. All pieces production-shaped.

#define IGNORE_IDX (-100)

constexpr int B = 8;
constexpr int D = 32;
constexpr int K = 64;
constexpr int NPTS = 131072;           // fixed problem shape
constexpr int RPG = 4;                 // x-rows per block (k1, k3_pd)
constexpr int DG  = D / RPG;           // 8
constexpr int SPA = 32;                // k1 spans/ (b,dg): 4096 pts/block
constexpr int SPB = 64;                // k3_pd spans: 2048 pts/block
constexpr int CH  = 128;               // k3_var chunks: 1024 pts/block
constexpr float DELTA_V = 0.5f;
constexpr float TWO_DELTA_D = 3.0f;
constexpr float PARAM_REG = 0.001f;

// ws float offsets
constexpr size_t OFF_MU  = (size_t)B * DG * SPA * 256;        // part: 524288
constexpr size_t OFF_VP  = OFF_MU + B * K * D;                // mu: 16384
constexpr size_t OFF_CNT = OFF_VP + (size_t)B * CH * K;       // vpart: 65536
constexpr size_t OFF_ID  = OFF_CNT + B * K;                   // cnt(int): 512
constexpr size_t OFF_PD  = OFF_ID + (size_t)B * NPTS / 4;     // id8: 262144 slots
constexpr size_t OFF_CTL = OFF_PD + (size_t)B * DG * NPTS;    // pd: 8388608

// ---------------------------------------------------------------- K5: pure-read control (m13 shape)
__global__ __launch_bounds__(256) void k5_ctl(const float* __restrict__ x,
                                              float* __restrict__ ctl)
{
    const size_t total = (size_t)B * D * NPTS / 4;   // float4 count: 8,388,608
    const size_t nt    = (size_t)gridDim.x * 256;
    const float4* xv   = (const float4*)x;
    float s = 0.f;
    for (size_t i = (size_t)blockIdx.x * 256 + threadIdx.x; i < total; i += nt) {
        const float4 f = xv[i];
        s += f.x + f.y + f.z + f.w;
    }
    for (int o = 32; o > 0; o >>= 1) s += __shfl_down(s, o, 64);
    __shared__ float s_w[4];
    if ((threadIdx.x & 63) == 0) s_w[threadIdx.x >> 6] = s;
    __syncthreads();
    if (threadIdx.x == 0) ctl[blockIdx.x] = s_w[0] + s_w[1] + s_w[2] + s_w[3];
}

// ---------------------------------------------------------------- K0: ids + counts
__global__ __launch_bounds__(256) void k0_ids(
    const int* __restrict__ sem, const int* __restrict__ inst,
    unsigned char* __restrict__ id8, int* __restrict__ cnt)
{
    __shared__ int s_cnt[K];
    const int t = threadIdx.x;
    const int b = blockIdx.x / (NPTS / 2048);
    if (t < K) s_cnt[t] = 0;
    __syncthreads();

    const int base = blockIdx.x * 2048 + t * 8;
    const int4 c0 = *(const int4*)(sem + base);
    const int4 c1 = *(const int4*)(sem + base + 4);
    const int4 i0 = *(const int4*)(inst + base);
    const int4 i1 = *(const int4*)(inst + base + 4);
    const int cl[8] = {c0.x, c0.y, c0.z, c0.w, c1.x, c1.y, c1.z, c1.w};
    const int il[8] = {i0.x, i0.y, i0.z, i0.w, i1.x, i1.y, i1.z, i1.w};

    unsigned w0 = 0, w1 = 0;
#pragma unroll
    for (int j = 0; j < 8; ++j) {
        const bool v = (cl[j] != IGNORE_IDX);
        int q = (cl[j] == 1) ? 0 : il[j];
        q = (q < 0) ? 0 : (q > K - 1 ? K - 1 : q);
        if (v) atomicAdd(&s_cnt[q], 1);
        const unsigned byte = v ? (unsigned)q : 255u;
        if (j < 4) w0 |= byte << (8 * j);
        else       w1 |= byte << (8 * (j - 4));
    }
    *(uint2*)(id8 + base) = make_uint2(w0, w1);
    __syncthreads();

    if (t < K) {
        const int c = s_cnt[t];
        if (c) atomicAdd(&cnt[b * K + t], c);
    }
}

// ---------------------------------------------------------------- K1: partial sums, 8 blocks/CU, pipelined
__global__ __launch_bounds__(256) void k1_sum(
    const float* __restrict__ x, const unsigned char* __restrict__ id8,
    float* __restrict__ part)
{
    __shared__ float s_acc[4][RPG][K];   // wave-private, 4KB
    const int t = threadIdx.x, w = t >> 6;
    const int blk = blockIdx.x;
    const int sp = blk & (SPA - 1);
    const int dg = (blk / SPA) & (DG - 1);
    const int b  = blk / (SPA * DG);

    for (int i = t; i < 4 * RPG * K; i += 256) ((float*)s_acc)[i] = 0.f;
    __syncthreads();

    const float* xb = x + ((size_t)b * D + dg * RPG) * NPTS + sp * 4096;
    const unsigned char* idb = id8 + (size_t)b * NPTS + sp * 4096;

    // 2-stage pipeline over 4 groups of 4 pts
    unsigned idw_n = *(const unsigned*)(idb + t * 4);
    float4 f_n[RPG];
#pragma unroll
    for (int r = 0; r < RPG; ++r)
        f_n[r] = *(const float4*)(xb + (size_t)r * NPTS + t * 4);

#pragma unroll
    for (int g = 0; g < 4; ++g) {
        const unsigned idw = idw_n;
        float fr[RPG][4];
#pragma unroll
        for (int r = 0; r < RPG; ++r) {
            fr[r][0] = f_n[r].x; fr[r][1] = f_n[r].y;
            fr[r][2] = f_n[r].z; fr[r][3] = f_n[r].w;
        }
        if (g < 3) {                          // issue next group's loads first
            const int nb = (g + 1) * 1024 + t * 4;
            idw_n = *(const unsigned*)(idb + nb);
#pragma unroll
            for (int r = 0; r < RPG; ++r)
                f_n[r] = *(const float4*)(xb + (size_t)r * NPTS + nb);
        }
#pragma unroll
        for (int j = 0; j < 4; ++j) {
            const unsigned id = (idw >> (8 * j)) & 255u;
            if (id < 64u) {
#pragma unroll
                for (int r = 0; r < RPG; ++r)
                    unsafeAtomicAdd(&s_acc[w][r][id], fr[r][j]);
            }
        }
    }
    __syncthreads();

    float* dst = part + (size_t)blk * 256;
    for (int i = t; i < 256; i += 256)
        dst[i] = ((float*)s_acc)[0 * 256 + i] + ((float*)s_acc)[1 * 256 + i]
               + ((float*)s_acc)[2 * 256 + i] + ((float*)s_acc)[3 * 256 + i];
}

// ---------------------------------------------------------------- K2: reduce -> mu
__global__ __launch_bounds__(256) void k2_mu(const float* __restrict__ part,
                                             const int* __restrict__ cnt,
                                             float* __restrict__ mu)
{
    const int gid  = blockIdx.x * 256 + threadIdx.x;   // B*K*D = 16384
    const int b    = gid >> 11;
    const int cell = gid & 2047;
    const int k = cell >> 5, d = cell & 31;
    const int dg = d >> 2, r = d & 3;

    float s = 0.f;
#pragma unroll 8
    for (int sp = 0; sp < SPA; ++sp)
        s += part[(size_t)(((b * DG + dg) * SPA) + sp) * 256 + r * K + k];
    mu[(size_t)b * K * D + k * D + d] = s / ((float)cnt[b * K + k] + 1e-8f);
}

// ---------------------------------------------------------------- K3a: per-dgroup partial L1 distances
__global__ __launch_bounds__(256) void k3_pd(
    const float* __restrict__ x, const unsigned char* __restrict__ id8,
    const float* __restrict__ mu, float* __restrict__ pd)
{
    __shared__ float s_mu[RPG][K];
    const int t = threadIdx.x;
    const int blk = blockIdx.x;
    const int sp = blk & (SPB - 1);
    const int dg = (blk / SPB) & (DG - 1);
    const int b  = blk / (SPB * DG);

    {   // i = r*64 + k
        const int r = t >> 6, k = t & 63;
        s_mu[r][k] = mu[((size_t)b * K + k) * D + dg * RPG + r];
    }
    __syncthreads();

    const float* xb = x + ((size_t)b * D + dg * RPG) * NPTS + sp * 2048;
    const unsigned char* idb = id8 + (size_t)b * NPTS + sp * 2048;
    float* pdb = pd + ((size_t)b * DG + dg) * NPTS + sp * 2048;

    unsigned idw_n = *(const unsigned*)(idb + t * 4);
    float4 f_n[RPG];
#pragma unroll
    for (int r = 0; r < RPG; ++r)
        f_n[r] = *(const float4*)(xb + (size_t)r * NPTS + t * 4);

#pragma unroll
    for (int g = 0; g < 2; ++g) {
        const unsigned idw = idw_n;
        float fr[RPG][4];
#pragma unroll
        for (int r = 0; r < RPG; ++r) {
            fr[r][0] = f_n[r].x; fr[r][1] = f_n[r].y;
            fr[r][2] = f_n[r].z; fr[r][3] = f_n[r].w;
        }
        if (g < 1) {
            const int nb = 1024 + t * 4;
            idw_n = *(const unsigned*)(idb + nb);
#pragma unroll
            for (int r = 0; r < RPG; ++r)
                f_n[r] = *(const float4*)(xb + (size_t)r * NPTS + nb);
        }
        float4 out;
        float* po = &out.x;
#pragma unroll
        for (int j = 0; j < 4; ++j) {
            const unsigned id = (idw >> (8 * j)) & 255u;
            const int idc = (id < 64u) ? (int)id : 0;
            float s = 0.f;
#pragma unroll
            for (int r = 0; r < RPG; ++r) s += fabsf(fr[r][j] - s_mu[r][idc]);
            po[j] = s;
        }
        *(float4*)(pdb + g * 1024 + t * 4) = out;
    }
}

// ---------------------------------------------------------------- K3b: sum planes, hinge, per-cluster var
__global__ __launch_bounds__(256) void k3_var(
    const float* __restrict__ pd, const unsigned char* __restrict__ id8,
    float* __restrict__ vpart)
{
    __shared__ float s_var[4][K];        // wave-private
    const int t = threadIdx.x, w = t >> 6;
    const int b  = blockIdx.x / CH;
    const int ch = blockIdx.x - b * CH;

    for (int i = t; i < 4 * K; i += 256) ((float*)s_var)[i] = 0.f;
    __syncthreads();

    const int n0 = ch * 1024 + t * 4;
    const unsigned idw = *(const unsigned*)(id8 + (size_t)b * NPTS + n0);

    float4 p[DG];                         // 8 independent plane loads
#pragma unroll
    for (int dg = 0; dg < DG; ++dg)
        p[dg] = *(const float4*)(pd + ((size_t)b * DG + dg) * NPTS + n0);

    float dist[4];
#pragma unroll
    for (int j = 0; j < 4; ++j) {
        const float* pf0 = &p[0].x;
        dist[j] = pf0[j];
    }
#pragma unroll
    for (int dg = 1; dg < DG; ++dg) {
        const float* pf = &p[dg].x;
#pragma unroll
        for (int j = 0; j < 4; ++j) dist[j] += pf[j];
    }
#pragma unroll
    for (int j = 0; j < 4; ++j) {
        const unsigned id = (idw >> (8 * j)) & 255u;
        if (id < 64u) {
            const float h = fmaxf(dist[j] - DELTA_V, 0.f);
            if (h > 0.f) unsafeAtomicAdd(&s_var[w][id], h * h);
        }
    }
    __syncthreads();

    if (t < K)
        vpart[((size_t)b * CH + ch) * K + t] =
            s_var[0][t] + s_var[1][t] + s_var[2][t] + s_var[3][t];
}

// ---------------------------------------------------------------- K4: finalize (1 block)
__device__ float block_reduce_sum512(float v, float* s_buf) {
    for (int o = 32; o > 0; o >>= 1) v += __shfl_down(v, o, 64);
    const int wid  = threadIdx.x >> 6;
    const int lane = threadIdx.x & 63;
    if (lane == 0) s_buf[wid] = v;
    __syncthreads();
    float r = 0.f;
    if (threadIdx.x == 0)
        for (int w = 0; w < 8; ++w) r += s_buf[w];
    __syncthreads();
    return r;
}

__global__ __launch_bounds__(512) void k4_final(const float* __restrict__ mu,
                                                const int* __restrict__ cnt,
                                                const float* __restrict__ vpart,
                                                float* __restrict__ out)
{
    __shared__ float s_mu[K][D + 1];
    __shared__ float s_cnt[B * K];
    __shared__ float s_varseg[B * K];
    __shared__ float s_red[8];

    const int t = threadIdx.x;
    s_cnt[t] = (float)cnt[t];
    __syncthreads();

    {
        const int b = t >> 6, k = t & 63;
        float vs = 0.f;
        for (int ch = 0; ch < CH; ++ch)
            vs += vpart[((size_t)b * CH + ch) * K + k];
        s_varseg[t] = vs / (s_cnt[t] + 1e-8f);
    }
    __syncthreads();

    float acc_loss = 0.f, acc_var = 0.f, acc_dist = 0.f, acc_reg = 0.f;

    for (int b = 0; b < B; ++b) {
        for (int i = t; i < K * D; i += 512) s_mu[i >> 5][i & 31] = mu[(size_t)b * K * D + i];
        __syncthreads();

        float distPart = 0.f;
        for (int p = t; p < K * K; p += 512) {
            const int i = p >> 6, j = p & 63;
            if (i != j && s_cnt[b * K + i] > 0.f && s_cnt[b * K + j] > 0.f) {
                float dsum = 0.f;
#pragma unroll
                for (int d = 0; d < D; ++d) dsum += fabsf(s_mu[i][d] - s_mu[j][d]);
                const float h = fmaxf(TWO_DELTA_D - dsum, 0.f);
                distPart += h * h;
            }
        }
        float regPart = 0.f;
        for (int i = t; i < K * D; i += 512) {
            const int k = i >> 5;
            if (s_cnt[b * K + k] > 0.f) regPart += fabsf(s_mu[k][i & 31]);
        }

        const float distSum = block_reduce_sum512(distPart, s_red);
        const float regSum  = block_reduce_sum512(regPart,  s_red);

        if (t == 0) {
            float np = 0.f, varSum = 0.f;
            for (int k = 0; k < K; ++k) {
                np     += (s_cnt[b * K + k] > 0.f) ? 1.f : 0.f;
                varSum += s_varseg[b * K + k];
            }
            const float n_inst = fmaxf(np, 1.0f);
            const float npairs = np * np - np;
            const float l_var  = varSum / n_inst;
            const float l_dist = (npairs > 0.f) ? (distSum / fmaxf(npairs, 1.0f)) : 0.f;
            const float l_reg  = PARAM_REG * (regSum / n_inst);
            acc_loss += l_var + l_dist + l_reg;
            acc_var  += l_var;
            acc_dist += l_dist;
            acc_reg  += l_reg;
        }
        __syncthreads();
    }

    if (t == 0) {
        const float invB = 1.0f / (float)B;
        out[0] = acc_loss * invB;
        out[1] = acc_var  * invB;
        out[2] = acc_dist * invB;
        out[3] = acc_reg  * invB;
    }
}

// ---------------------------------------------------------------- launch
extern "C" void kernel_launch(void* const* d_in, const int* in_sizes, int n_in,
                              void* d_out, int out_size, void* d_ws, size_t ws_size,
                              hipStream_t stream) {
    const float* x    = (const float*)d_in[0];
    const int*   sem  = (const int*)d_in[1];
    const int*   inst = (const int*)d_in[2];
    float*       out  = (float*)d_out;
    float*       ws   = (float*)d_ws;

    float*         part  = ws;
    float*         mu    = ws + OFF_MU;
    float*         vpart = ws + OFF_VP;
    int*           cnt   = (int*)(ws + OFF_CNT);
    unsigned char* id8   = (unsigned char*)(ws + OFF_ID);
    float*         pd    = ws + OFF_PD;
    float*         ctl   = ws + OFF_CTL;

    hipMemsetAsync(cnt, 0, B * K * sizeof(int), stream);

    k5_ctl<<<dim3(2048), dim3(256), 0, stream>>>(x, ctl);
    k0_ids<<<dim3(B * NPTS / 2048), dim3(256), 0, stream>>>(sem, inst, id8, cnt);
    k1_sum<<<dim3(B * DG * SPA), dim3(256), 0, stream>>>(x, id8, part);
    k2_mu<<<dim3(B * K * D / 256), dim3(256), 0, stream>>>(part, cnt, mu);
    k3_pd<<<dim3(B * DG * SPB), dim3(256), 0, stream>>>(x, id8, mu, pd);
    k3_var<<<dim3(B * CH), dim3(256), 0, stream>>>(pd, id8, vpart);
    k4_final<<<dim3(1), dim3(512), 0, stream>>>(mu, cnt, vpart, out);
}

// Round 6
// 306.836 us; speedup vs baseline: 1.5227x; 1.5227x over previous
//
#include <hip/hip_runtime.h>

// DiscriminativeLoss — B=8, D=32, N=131072, K=64.
// R6: eliminate scattered LDS from the per-point-per-dim inner loops.
// Evidence: every R1-R5 variant performed exactly 2048 scattered-index LDS
// wave-ops per CU (ds_add or ds_read with per-lane random cluster id) and
// every one took ~175us (~200cy/op) with VALU/VMEM idle. Fix: the id
// dependency becomes a one-hot MFMA operand instead of an LDS address.
//   k0: pack ids (1B/pt) + counts
//   k1: S[d][k] = x · onehot^T   via mfma_32x32x16_bf16, hi/lo split
//   k2: reduce partials -> mu[b][d][k]
//   k3: mu_pt = mu · onehot (MFMA gather), |x-mu_pt| streamed, hinge,
//       ONE scatter per point (32x fewer scattered ops)
//   k4: finalize

typedef unsigned char uchar;
typedef __attribute__((ext_vector_type(8)))  short bf16x8;
typedef __attribute__((ext_vector_type(16))) float f32x16;

#define IGNORE_IDX (-100)

constexpr int B = 8;
constexpr int D = 32;
constexpr int K = 64;
constexpr int NPTS = 131072;
constexpr int BPB  = 128;              // blocks per batch (k1,k3)
constexpr int SPAN = 1024;             // points per block
constexpr float DELTA_V = 0.5f;
constexpr float TWO_DELTA_D = 3.0f;
constexpr float PARAM_REG = 0.001f;

// ws float offsets
constexpr size_t OFF_MU  = (size_t)B * BPB * 2048;     // part: 2,097,152
constexpr size_t OFF_VP  = OFF_MU + (size_t)B * 2048;  // mu: 16,384
constexpr size_t OFF_CNT = OFF_VP + (size_t)B * BPB * K; // vpart: 65,536
constexpr size_t OFF_ID  = OFF_CNT + (size_t)B * K;    // cnt(int): 512

__device__ inline short f2bf_rne(float f) {
    unsigned u = __float_as_uint(f);
    u = (u + 0x7FFFu + ((u >> 16) & 1u)) >> 16;
    return (short)u;
}
__device__ inline float bf2f(short h) {
    return __uint_as_float(((unsigned)(unsigned short)h) << 16);
}

// ---------------------------------------------------------------- K0: ids + counts
__global__ __launch_bounds__(256) void k0_ids(
    const int* __restrict__ sem, const int* __restrict__ inst,
    uchar* __restrict__ id8, int* __restrict__ cnt)
{
    __shared__ int s_cnt[K];
    const int t = threadIdx.x;
    const int b = blockIdx.x / (NPTS / 2048);
    if (t < K) s_cnt[t] = 0;
    __syncthreads();

    const int base = blockIdx.x * 2048 + t * 8;
    const int4 c0 = *(const int4*)(sem + base);
    const int4 c1 = *(const int4*)(sem + base + 4);
    const int4 i0 = *(const int4*)(inst + base);
    const int4 i1 = *(const int4*)(inst + base + 4);
    const int cl[8] = {c0.x, c0.y, c0.z, c0.w, c1.x, c1.y, c1.z, c1.w};
    const int il[8] = {i0.x, i0.y, i0.z, i0.w, i1.x, i1.y, i1.z, i1.w};

    unsigned w0 = 0, w1 = 0;
#pragma unroll
    for (int j = 0; j < 8; ++j) {
        const bool v = (cl[j] != IGNORE_IDX);
        int q = (cl[j] == 1) ? 0 : il[j];
        q = (q < 0) ? 0 : (q > K - 1 ? K - 1 : q);
        if (v) atomicAdd(&s_cnt[q], 1);
        const unsigned byte = v ? (unsigned)q : 255u;
        if (j < 4) w0 |= byte << (8 * j);
        else       w1 |= byte << (8 * (j - 4));
    }
    *(uint2*)(id8 + base) = make_uint2(w0, w1);
    __syncthreads();

    if (t < K) {
        const int c = s_cnt[t];
        if (c) atomicAdd(&cnt[b * K + t], c);
    }
}

// ---------------------------------------------------------------- K1: segment sums via MFMA onehot
// C[d=32][k=32-half] += A(x)[d=32][n=16] * B(onehot)[n=16][k=32-half]
// A lane map: m=lane&31, k-dim=(lane>>5)*8+j.  B: n-col=lane&31, k-dim same.
// C: col=lane&31, row=(reg&3)+8*(reg>>2)+4*(lane>>5)  [m74/m101 verified].
__global__ __launch_bounds__(256) void k1_mfma(
    const float* __restrict__ x, const uchar* __restrict__ id8,
    float* __restrict__ part)
{
    __shared__ float s_part[4][2048];
    const int t = threadIdx.x, w = t >> 6, L = t & 63;
    const int g = L >> 5, ln = L & 31;
    const int blk = blockIdx.x, b = blk >> 7, sp = blk & (BPB - 1);

    const float* xrow = x + (size_t)b * D * NPTS + (size_t)ln * NPTS + sp * SPAN;
    const uchar* idb  = id8 + (size_t)b * NPTS + sp * SPAN;

    f32x16 acc0, acc1;
#pragma unroll
    for (int i = 0; i < 16; ++i) { acc0[i] = 0.f; acc1[i] = 0.f; }

    for (int it = 0; it < SPAN / 64; ++it) {          // 16 iters, 16 pts/wave each
        const int n0 = (it * 4 + w) * 16;
        const uint2 idq = *(const uint2*)(idb + n0 + g * 8);
        const float4 xa = *(const float4*)(xrow + n0 + g * 8);
        const float4 xc = *(const float4*)(xrow + n0 + g * 8 + 4);
        const float xs[8] = {xa.x, xa.y, xa.z, xa.w, xc.x, xc.y, xc.z, xc.w};
        bf16x8 Ah, Al, B0, B1;
#pragma unroll
        for (int j = 0; j < 8; ++j) {
            const short h = f2bf_rne(xs[j]);
            Ah[j] = h;
            Al[j] = f2bf_rne(xs[j] - bf2f(h));
            const unsigned byte = ((j < 4) ? (idq.x >> (8 * j)) : (idq.y >> (8 * (j - 4)))) & 255u;
            B0[j] = (byte == (unsigned)ln)        ? (short)0x3F80 : (short)0;
            B1[j] = (byte == (unsigned)(ln + 32)) ? (short)0x3F80 : (short)0;
        }
        acc0 = __builtin_amdgcn_mfma_f32_32x32x16_bf16(Ah, B0, acc0, 0, 0, 0);
        acc0 = __builtin_amdgcn_mfma_f32_32x32x16_bf16(Al, B0, acc0, 0, 0, 0);
        acc1 = __builtin_amdgcn_mfma_f32_32x32x16_bf16(Ah, B1, acc1, 0, 0, 0);
        acc1 = __builtin_amdgcn_mfma_f32_32x32x16_bf16(Al, B1, acc1, 0, 0, 0);
    }

#pragma unroll
    for (int r = 0; r < 16; ++r) {
        const int row = (r & 3) + 8 * (r >> 2) + 4 * g;   // d
        s_part[w][row * 64 + ln]      = acc0[r];          // k = ln
        s_part[w][row * 64 + ln + 32] = acc1[r];          // k = ln+32
    }
    __syncthreads();

    float* dst = part + (size_t)blk * 2048;               // layout [d][k]
    for (int i = t; i < 2048; i += 256)
        dst[i] = s_part[0][i] + s_part[1][i] + s_part[2][i] + s_part[3][i];
}

// ---------------------------------------------------------------- K2: reduce -> mu[b][d][64]
__global__ __launch_bounds__(256) void k2_mu(const float* __restrict__ part,
                                             const int* __restrict__ cnt,
                                             float* __restrict__ mu)
{
    const int gid  = blockIdx.x * 256 + threadIdx.x;      // B*2048 = 16384
    const int b    = gid >> 11;
    const int cell = gid & 2047;                          // d*64 + k
    const int k    = cell & 63;
    float s = 0.f;
    for (int blk = 0; blk < BPB; ++blk)
        s += part[((size_t)(b * BPB + blk) << 11) + cell];
    mu[(size_t)b * 2048 + cell] = s / ((float)cnt[b * K + k] + 1e-8f);
}

// ---------------------------------------------------------------- K3: var via MFMA gather
// mu_pt[d][n] = mu[d][k] @ onehot[k][n]; dist = sum_d |x - mu_pt|; 1 scatter/pt
__global__ __launch_bounds__(256) void k3_mfma(
    const float* __restrict__ x, const uchar* __restrict__ id8,
    const float* __restrict__ mu, float* __restrict__ vpart)
{
    __shared__ float s_var[K];
    const int t = threadIdx.x, w = t >> 6, L = t & 63;
    const int g = L >> 5, ln = L & 31;
    const int blk = blockIdx.x, b = blk >> 7, sp = blk & (BPB - 1);
    if (t < K) s_var[t] = 0.f;

    // A-frags: mu[d=ln][k = c*16 + g*8 + j], hi/lo
    bf16x8 MAh[4], MAl[4];
    const float* mrow = mu + (size_t)b * 2048 + ln * 64;
#pragma unroll
    for (int c = 0; c < 4; ++c) {
        const float4 m0 = *(const float4*)(mrow + c * 16 + g * 8);
        const float4 m1 = *(const float4*)(mrow + c * 16 + g * 8 + 4);
        const float ms[8] = {m0.x, m0.y, m0.z, m0.w, m1.x, m1.y, m1.z, m1.w};
#pragma unroll
        for (int j = 0; j < 8; ++j) {
            const short h = f2bf_rne(ms[j]);
            MAh[c][j] = h;
            MAl[c][j] = f2bf_rne(ms[j] - bf2f(h));
        }
    }
    __syncthreads();

    const float* xb  = x + (size_t)b * D * NPTS + sp * SPAN;
    const uchar* idb = id8 + (size_t)b * NPTS + sp * SPAN;

    for (int it = 0; it < SPAN / 128; ++it) {             // 8 iters, 32 pts/wave
        const int n0 = (it * 4 + w) * 32;
        const unsigned myid = idb[n0 + ln];               // id of this lane's point
        f32x16 acc;
#pragma unroll
        for (int i = 0; i < 16; ++i) acc[i] = 0.f;
#pragma unroll
        for (int c = 0; c < 4; ++c) {
            bf16x8 Bc;
#pragma unroll
            for (int j = 0; j < 8; ++j)
                Bc[j] = (myid == (unsigned)(c * 16 + g * 8 + j)) ? (short)0x3F80 : (short)0;
            acc = __builtin_amdgcn_mfma_f32_32x32x16_bf16(MAh[c], Bc, acc, 0, 0, 0);
            acc = __builtin_amdgcn_mfma_f32_32x32x16_bf16(MAl[c], Bc, acc, 0, 0, 0);
        }
        float s = 0.f;
#pragma unroll
        for (int r = 0; r < 16; ++r) {
            const int row = (r & 3) + 8 * (r >> 2) + 4 * g;
            const float xv = xb[(size_t)row * NPTS + n0 + ln];   // coalesced
            s += fabsf(xv - acc[r]);
        }
        s += __shfl_xor(s, 32, 64);                       // full 32-dim sum
        if (g == 0 && myid < 64u) {
            const float h = fmaxf(s - DELTA_V, 0.f);
            if (h > 0.f) unsafeAtomicAdd(&s_var[myid], h * h);
        }
    }
    __syncthreads();
    if (t < K) vpart[(size_t)blk * K + t] = s_var[t];
}

// ---------------------------------------------------------------- K4: finalize (1 block)
__device__ float block_reduce_sum512(float v, float* s_buf) {
    for (int o = 32; o > 0; o >>= 1) v += __shfl_down(v, o, 64);
    const int wid  = threadIdx.x >> 6;
    const int lane = threadIdx.x & 63;
    if (lane == 0) s_buf[wid] = v;
    __syncthreads();
    float r = 0.f;
    if (threadIdx.x == 0)
        for (int w = 0; w < 8; ++w) r += s_buf[w];
    __syncthreads();
    return r;
}

__global__ __launch_bounds__(512) void k4_final(const float* __restrict__ mu,
                                                const int* __restrict__ cnt,
                                                const float* __restrict__ vpart,
                                                float* __restrict__ out)
{
    __shared__ float s_mu[K][D + 1];
    __shared__ float s_cnt[B * K];
    __shared__ float s_varseg[B * K];
    __shared__ float s_red[8];

    const int t = threadIdx.x;
    s_cnt[t] = (float)cnt[t];
    __syncthreads();

    {
        const int b = t >> 6, k = t & 63;
        float vs = 0.f;
        for (int ch = 0; ch < BPB; ++ch)
            vs += vpart[((size_t)(b * BPB + ch)) * K + k];
        s_varseg[t] = vs / (s_cnt[t] + 1e-8f);
    }
    __syncthreads();

    float acc_loss = 0.f, acc_var = 0.f, acc_dist = 0.f, acc_reg = 0.f;

    for (int b = 0; b < B; ++b) {
        // mu stored [d][k]; fill s_mu[k][d]
        for (int i = t; i < K * D; i += 512)
            s_mu[i >> 5][i & 31] = mu[(size_t)b * 2048 + (i & 31) * 64 + (i >> 5)];
        __syncthreads();

        float distPart = 0.f;
        for (int p = t; p < K * K; p += 512) {
            const int i = p >> 6, j = p & 63;
            if (i != j && s_cnt[b * K + i] > 0.f && s_cnt[b * K + j] > 0.f) {
                float dsum = 0.f;
#pragma unroll
                for (int d = 0; d < D; ++d) dsum += fabsf(s_mu[i][d] - s_mu[j][d]);
                const float h = fmaxf(TWO_DELTA_D - dsum, 0.f);
                distPart += h * h;
            }
        }
        float regPart = 0.f;
        for (int i = t; i < K * D; i += 512) {
            const int k = i >> 5;
            if (s_cnt[b * K + k] > 0.f) regPart += fabsf(s_mu[k][i & 31]);
        }

        const float distSum = block_reduce_sum512(distPart, s_red);
        const float regSum  = block_reduce_sum512(regPart,  s_red);

        if (t == 0) {
            float np = 0.f, varSum = 0.f;
            for (int k = 0; k < K; ++k) {
                np     += (s_cnt[b * K + k] > 0.f) ? 1.f : 0.f;
                varSum += s_varseg[b * K + k];
            }
            const float n_inst = fmaxf(np, 1.0f);
            const float npairs = np * np - np;
            const float l_var  = varSum / n_inst;
            const float l_dist = (npairs > 0.f) ? (distSum / fmaxf(npairs, 1.0f)) : 0.f;
            const float l_reg  = PARAM_REG * (regSum / n_inst);
            acc_loss += l_var + l_dist + l_reg;
            acc_var  += l_var;
            acc_dist += l_dist;
            acc_reg  += l_reg;
        }
        __syncthreads();
    }

    if (t == 0) {
        const float invB = 1.0f / (float)B;
        out[0] = acc_loss * invB;
        out[1] = acc_var  * invB;
        out[2] = acc_dist * invB;
        out[3] = acc_reg  * invB;
    }
}

// ---------------------------------------------------------------- launch
extern "C" void kernel_launch(void* const* d_in, const int* in_sizes, int n_in,
                              void* d_out, int out_size, void* d_ws, size_t ws_size,
                              hipStream_t stream) {
    const float* x    = (const float*)d_in[0];
    const int*   sem  = (const int*)d_in[1];
    const int*   inst = (const int*)d_in[2];
    float*       out  = (float*)d_out;
    float*       ws   = (float*)d_ws;

    float* part  = ws;
    float* mu    = ws + OFF_MU;
    float* vpart = ws + OFF_VP;
    int*   cnt   = (int*)(ws + OFF_CNT);
    uchar* id8   = (uchar*)(ws + OFF_ID);

    hipMemsetAsync(cnt, 0, B * K * sizeof(int), stream);

    k0_ids<<<dim3(B * NPTS / 2048), dim3(256), 0, stream>>>(sem, inst, id8, cnt);
    k1_mfma<<<dim3(B * BPB), dim3(256), 0, stream>>>(x, id8, part);
    k2_mu<<<dim3(B * K * D / 256), dim3(256), 0, stream>>>(part, cnt, mu);
    k3_mfma<<<dim3(B * BPB), dim3(256), 0, stream>>>(x, id8, mu, vpart);
    k4_final<<<dim3(1), dim3(512), 0, stream>>>(mu, cnt, vpart, out);
}

// Round 7
// 257.277 us; speedup vs baseline: 1.8160x; 1.1926x over previous
//
#include <hip/hip_runtime.h>

// DiscriminativeLoss — B=8, D=32, N=131072, K=64.
// R6 win: one-hot MFMA replaced scattered-LDS inner loops (467->307us; every
// R1-R5 design was pinned at ~175us/pass by ~2048 scattered LDS wave-ops/CU).
// R7: (a) drop the hi/lo bf16 split — error budget: mu abs err ~1e-4 vs
// dist~25, hinge~630, threshold 2% -> hi-only is 1000x inside budget; halves
// MFMA count AND the f2bf conversion VALU that now dominates k1/k3.
// (b) k4 parallelized: 8 blocks (one per batch) + atomicAdd into zeroed out.

typedef unsigned char uchar;
typedef __attribute__((ext_vector_type(8)))  short bf16x8;
typedef __attribute__((ext_vector_type(16))) float f32x16;

#define IGNORE_IDX (-100)

constexpr int B = 8;
constexpr int D = 32;
constexpr int K = 64;
constexpr int NPTS = 131072;
constexpr int BPB  = 128;              // blocks per batch (k1,k3)
constexpr int SPAN = 1024;             // points per block
constexpr float DELTA_V = 0.5f;
constexpr float TWO_DELTA_D = 3.0f;
constexpr float PARAM_REG = 0.001f;

// ws float offsets
constexpr size_t OFF_MU  = (size_t)B * BPB * 2048;       // part: 2,097,152
constexpr size_t OFF_VP  = OFF_MU + (size_t)B * 2048;    // mu: 16,384
constexpr size_t OFF_CNT = OFF_VP + (size_t)B * BPB * K; // vpart: 65,536
constexpr size_t OFF_ID  = OFF_CNT + (size_t)B * K;      // cnt(int): 512

__device__ inline short f2bf_rne(float f) {
    unsigned u = __float_as_uint(f);
    u = (u + 0x7FFFu + ((u >> 16) & 1u)) >> 16;
    return (short)u;
}

// ---------------------------------------------------------------- K0: ids + counts
__global__ __launch_bounds__(256) void k0_ids(
    const int* __restrict__ sem, const int* __restrict__ inst,
    uchar* __restrict__ id8, int* __restrict__ cnt)
{
    __shared__ int s_cnt[K];
    const int t = threadIdx.x;
    const int b = blockIdx.x / (NPTS / 2048);
    if (t < K) s_cnt[t] = 0;
    __syncthreads();

    const int base = blockIdx.x * 2048 + t * 8;
    const int4 c0 = *(const int4*)(sem + base);
    const int4 c1 = *(const int4*)(sem + base + 4);
    const int4 i0 = *(const int4*)(inst + base);
    const int4 i1 = *(const int4*)(inst + base + 4);
    const int cl[8] = {c0.x, c0.y, c0.z, c0.w, c1.x, c1.y, c1.z, c1.w};
    const int il[8] = {i0.x, i0.y, i0.z, i0.w, i1.x, i1.y, i1.z, i1.w};

    unsigned w0 = 0, w1 = 0;
#pragma unroll
    for (int j = 0; j < 8; ++j) {
        const bool v = (cl[j] != IGNORE_IDX);
        int q = (cl[j] == 1) ? 0 : il[j];
        q = (q < 0) ? 0 : (q > K - 1 ? K - 1 : q);
        if (v) atomicAdd(&s_cnt[q], 1);
        const unsigned byte = v ? (unsigned)q : 255u;
        if (j < 4) w0 |= byte << (8 * j);
        else       w1 |= byte << (8 * (j - 4));
    }
    *(uint2*)(id8 + base) = make_uint2(w0, w1);
    __syncthreads();

    if (t < K) {
        const int c = s_cnt[t];
        if (c) atomicAdd(&cnt[b * K + t], c);
    }
}

// ---------------------------------------------------------------- K1: segment sums via MFMA onehot
// C[d=32][khalf=32] += A(x)[d][n=16] * B(onehot)[n][khalf]
// A: m=lane&31, kdim=(lane>>5)*8+j.  B: ncol=lane&31, kdim same.
// C: col=lane&31, row=(reg&3)+8*(reg>>2)+4*(lane>>5)  [m74/m101 verified].
__global__ __launch_bounds__(256) void k1_mfma(
    const float* __restrict__ x, const uchar* __restrict__ id8,
    float* __restrict__ part)
{
    __shared__ float s_part[4][2048];
    const int t = threadIdx.x, w = t >> 6, L = t & 63;
    const int g = L >> 5, ln = L & 31;
    const int blk = blockIdx.x, b = blk >> 7, sp = blk & (BPB - 1);

    const float* xrow = x + (size_t)b * D * NPTS + (size_t)ln * NPTS + sp * SPAN;
    const uchar* idb  = id8 + (size_t)b * NPTS + sp * SPAN;

    f32x16 acc0, acc1;
#pragma unroll
    for (int i = 0; i < 16; ++i) { acc0[i] = 0.f; acc1[i] = 0.f; }

    for (int it = 0; it < SPAN / 64; ++it) {          // 16 iters, 16 pts/wave
        const int n0 = (it * 4 + w) * 16;
        const uint2 idq = *(const uint2*)(idb + n0 + g * 8);
        const float4 xa = *(const float4*)(xrow + n0 + g * 8);
        const float4 xc = *(const float4*)(xrow + n0 + g * 8 + 4);
        const float xs[8] = {xa.x, xa.y, xa.z, xa.w, xc.x, xc.y, xc.z, xc.w};
        bf16x8 Ah, B0, B1;
#pragma unroll
        for (int j = 0; j < 8; ++j) {
            Ah[j] = f2bf_rne(xs[j]);
            const unsigned byte = ((j < 4) ? (idq.x >> (8 * j)) : (idq.y >> (8 * (j - 4)))) & 255u;
            B0[j] = (byte == (unsigned)ln)        ? (short)0x3F80 : (short)0;
            B1[j] = (byte == (unsigned)(ln + 32)) ? (short)0x3F80 : (short)0;
        }
        acc0 = __builtin_amdgcn_mfma_f32_32x32x16_bf16(Ah, B0, acc0, 0, 0, 0);
        acc1 = __builtin_amdgcn_mfma_f32_32x32x16_bf16(Ah, B1, acc1, 0, 0, 0);
    }

#pragma unroll
    for (int r = 0; r < 16; ++r) {
        const int row = (r & 3) + 8 * (r >> 2) + 4 * g;   // d
        s_part[w][row * 64 + ln]      = acc0[r];          // k = ln
        s_part[w][row * 64 + ln + 32] = acc1[r];          // k = ln+32
    }
    __syncthreads();

    float* dst = part + (size_t)blk * 2048;               // layout [d][k]
    for (int i = t; i < 2048; i += 256)
        dst[i] = s_part[0][i] + s_part[1][i] + s_part[2][i] + s_part[3][i];
}

// ---------------------------------------------------------------- K2: reduce -> mu[b][d][64]
__global__ __launch_bounds__(256) void k2_mu(const float* __restrict__ part,
                                             const int* __restrict__ cnt,
                                             float* __restrict__ mu)
{
    const int gid  = blockIdx.x * 256 + threadIdx.x;      // B*2048 = 16384
    const int b    = gid >> 11;
    const int cell = gid & 2047;                          // d*64 + k
    const int k    = cell & 63;
    float s = 0.f;
    for (int blk = 0; blk < BPB; ++blk)
        s += part[((size_t)(b * BPB + blk) << 11) + cell];
    mu[(size_t)b * 2048 + cell] = s / ((float)cnt[b * K + k] + 1e-8f);
}

// ---------------------------------------------------------------- K3: var via MFMA gather
// mu_pt[d][n] = mu[d][k] @ onehot[k][n]; dist = sum_d |x - mu_pt|; 1 scatter/pt
__global__ __launch_bounds__(256) void k3_mfma(
    const float* __restrict__ x, const uchar* __restrict__ id8,
    const float* __restrict__ mu, float* __restrict__ vpart)
{
    __shared__ float s_var[K];
    const int t = threadIdx.x, w = t >> 6, L = t & 63;
    const int g = L >> 5, ln = L & 31;
    const int blk = blockIdx.x, b = blk >> 7, sp = blk & (BPB - 1);
    if (t < K) s_var[t] = 0.f;

    // A-frags: mu[d=ln][k = c*16 + g*8 + j], hi only (mu err ~1e-4 << budget)
    bf16x8 MAh[4];
    const float* mrow = mu + (size_t)b * 2048 + ln * 64;
#pragma unroll
    for (int c = 0; c < 4; ++c) {
        const float4 m0 = *(const float4*)(mrow + c * 16 + g * 8);
        const float4 m1 = *(const float4*)(mrow + c * 16 + g * 8 + 4);
        const float ms[8] = {m0.x, m0.y, m0.z, m0.w, m1.x, m1.y, m1.z, m1.w};
#pragma unroll
        for (int j = 0; j < 8; ++j) MAh[c][j] = f2bf_rne(ms[j]);
    }
    __syncthreads();

    const float* xb  = x + (size_t)b * D * NPTS + sp * SPAN;
    const uchar* idb = id8 + (size_t)b * NPTS + sp * SPAN;

    for (int it = 0; it < SPAN / 128; ++it) {             // 8 iters, 32 pts/wave
        const int n0 = (it * 4 + w) * 32;
        const unsigned myid = idb[n0 + ln];
        f32x16 acc;
#pragma unroll
        for (int i = 0; i < 16; ++i) acc[i] = 0.f;
#pragma unroll
        for (int c = 0; c < 4; ++c) {
            bf16x8 Bc;
#pragma unroll
            for (int j = 0; j < 8; ++j)
                Bc[j] = (myid == (unsigned)(c * 16 + g * 8 + j)) ? (short)0x3F80 : (short)0;
            acc = __builtin_amdgcn_mfma_f32_32x32x16_bf16(MAh[c], Bc, acc, 0, 0, 0);
        }
        float s = 0.f;
#pragma unroll
        for (int r = 0; r < 16; ++r) {
            const int row = (r & 3) + 8 * (r >> 2) + 4 * g;
            const float xv = xb[(size_t)row * NPTS + n0 + ln];   // coalesced
            s += fabsf(xv - acc[r]);
        }
        s += __shfl_xor(s, 32, 64);                       // full 32-dim sum
        if (g == 0 && myid < 64u) {
            const float h = fmaxf(s - DELTA_V, 0.f);
            if (h > 0.f) unsafeAtomicAdd(&s_var[myid], h * h);
        }
    }
    __syncthreads();
    if (t < K) vpart[(size_t)blk * K + t] = s_var[t];
}

// ---------------------------------------------------------------- K4: finalize (8 blocks, one per batch)
__device__ float block_reduce_sum512(float v, float* s_buf) {
    for (int o = 32; o > 0; o >>= 1) v += __shfl_down(v, o, 64);
    const int wid  = threadIdx.x >> 6;
    const int lane = threadIdx.x & 63;
    if (lane == 0) s_buf[wid] = v;
    __syncthreads();
    float r = 0.f;
    if (threadIdx.x == 0)
        for (int w = 0; w < 8; ++w) r += s_buf[w];
    __syncthreads();
    return r;
}

__global__ __launch_bounds__(512) void k4_final(const float* __restrict__ mu,
                                                const int* __restrict__ cnt,
                                                const float* __restrict__ vpart,
                                                float* __restrict__ out)
{
    const int b = blockIdx.x;
    __shared__ float s_mu[K][D + 1];
    __shared__ float s_cnt[K];
    __shared__ float s_vp[8][K];
    __shared__ float s_red[8];

    const int t = threadIdx.x;
    if (t < K) s_cnt[t] = (float)cnt[b * K + t];

    {   // vpart partial reduce: part=t>>6 owns chunks part*16..+16 for k=t&63
        const int k = t & 63, pr = t >> 6;
        float vs = 0.f;
#pragma unroll
        for (int ch = pr * 16; ch < pr * 16 + 16; ++ch)
            vs += vpart[((size_t)(b * BPB + ch)) * K + k];
        s_vp[pr][k] = vs;
    }
    for (int i = t; i < K * D; i += 512)     // mu stored [d][k] -> s_mu[k][d]
        s_mu[i >> 5][i & 31] = mu[(size_t)b * 2048 + (i & 31) * 64 + (i >> 5)];
    __syncthreads();

    float distPart = 0.f;
    for (int p = t; p < K * K; p += 512) {
        const int i = p >> 6, j = p & 63;
        if (i != j && s_cnt[i] > 0.f && s_cnt[j] > 0.f) {
            float dsum = 0.f;
#pragma unroll
            for (int d = 0; d < D; ++d) dsum += fabsf(s_mu[i][d] - s_mu[j][d]);
            const float h = fmaxf(TWO_DELTA_D - dsum, 0.f);
            distPart += h * h;
        }
    }
    float regPart = 0.f;
    for (int i = t; i < K * D; i += 512) {
        const int k = i >> 5;
        if (s_cnt[k] > 0.f) regPart += fabsf(s_mu[k][i & 31]);
    }
    float varPart = 0.f, npPart = 0.f;
    if (t < K) {
        float vs = 0.f;
#pragma unroll
        for (int pr = 0; pr < 8; ++pr) vs += s_vp[pr][t];
        varPart = vs / (s_cnt[t] + 1e-8f);
        npPart  = (s_cnt[t] > 0.f) ? 1.f : 0.f;
    }

    const float distSum = block_reduce_sum512(distPart, s_red);
    const float regSum  = block_reduce_sum512(regPart,  s_red);
    const float varSum  = block_reduce_sum512(varPart,  s_red);
    const float npSum   = block_reduce_sum512(npPart,   s_red);

    if (t == 0) {
        const float n_inst = fmaxf(npSum, 1.0f);
        const float npairs = npSum * npSum - npSum;
        const float l_var  = varSum / n_inst;
        const float l_dist = (npairs > 0.f) ? (distSum / fmaxf(npairs, 1.0f)) : 0.f;
        const float l_reg  = PARAM_REG * (regSum / n_inst);
        const float invB   = 1.0f / (float)B;
        unsafeAtomicAdd(out + 0, (l_var + l_dist + l_reg) * invB);
        unsafeAtomicAdd(out + 1, l_var  * invB);
        unsafeAtomicAdd(out + 2, l_dist * invB);
        unsafeAtomicAdd(out + 3, l_reg  * invB);
    }
}

// ---------------------------------------------------------------- launch
extern "C" void kernel_launch(void* const* d_in, const int* in_sizes, int n_in,
                              void* d_out, int out_size, void* d_ws, size_t ws_size,
                              hipStream_t stream) {
    const float* x    = (const float*)d_in[0];
    const int*   sem  = (const int*)d_in[1];
    const int*   inst = (const int*)d_in[2];
    float*       out  = (float*)d_out;
    float*       ws   = (float*)d_ws;

    float* part  = ws;
    float* mu    = ws + OFF_MU;
    float* vpart = ws + OFF_VP;
    int*   cnt   = (int*)(ws + OFF_CNT);
    uchar* id8   = (uchar*)(ws + OFF_ID);

    hipMemsetAsync(cnt, 0, B * K * sizeof(int), stream);
    hipMemsetAsync(out, 0, (size_t)out_size * sizeof(float), stream);

    k0_ids<<<dim3(B * NPTS / 2048), dim3(256), 0, stream>>>(sem, inst, id8, cnt);
    k1_mfma<<<dim3(B * BPB), dim3(256), 0, stream>>>(x, id8, part);
    k2_mu<<<dim3(B * K * D / 256), dim3(256), 0, stream>>>(part, cnt, mu);
    k3_mfma<<<dim3(B * BPB), dim3(256), 0, stream>>>(x, id8, mu, vpart);
    k4_final<<<dim3(B), dim3(512), 0, stream>>>(mu, cnt, vpart, out);
}

// Round 8
// 256.229 us; speedup vs baseline: 1.8234x; 1.0041x over previous
//
#include <hip/hip_runtime.h>

// DiscriminativeLoss — B=8, D=32, N=131072, K=64.
// R6: one-hot MFMA replaced scattered-LDS inner loops (the R1-R5 175us/pass
// floor was ~2048 scattered LDS wave-ops/CU at ~200cy each).
// R7: hi-only bf16 + parallel k4 (307->257us). Accounting: fixed harness
// overhead ~160us (512MB ws re-poison fills @76us visible in top-5), our
// kernels ~95us, VALU-bound on fragment construction.
// R8: slim fragment build: (a) k1 bf16 pack = bit-add 0x8000 + v_perm_b32
// (12 ops vs 40, bias-free round-half-away); (b) k3 one-hot via single 8-bit
// mask + expand + c-select (~41 ops vs ~80); (c) perm-pack MAh.

typedef unsigned char uchar;
typedef __attribute__((ext_vector_type(8)))  short bf16x8;
typedef __attribute__((ext_vector_type(16))) float f32x16;

#define IGNORE_IDX (-100)

constexpr int B = 8;
constexpr int D = 32;
constexpr int K = 64;
constexpr int NPTS = 131072;
constexpr int BPB  = 128;              // blocks per batch (k1,k3)
constexpr int SPAN = 1024;             // points per block
constexpr float DELTA_V = 0.5f;
constexpr float TWO_DELTA_D = 3.0f;
constexpr float PARAM_REG = 0.001f;

// ws float offsets
constexpr size_t OFF_MU  = (size_t)B * BPB * 2048;       // part: 2,097,152
constexpr size_t OFF_VP  = OFF_MU + (size_t)B * 2048;    // mu: 16,384
constexpr size_t OFF_CNT = OFF_VP + (size_t)B * BPB * K; // vpart: 65,536
constexpr size_t OFF_ID  = OFF_CNT + (size_t)B * K;      // cnt(int): 512

// pack two pre-rounded fp32 bit patterns into a bf16 pair (1 v_perm_b32)
__device__ inline unsigned bfpack(unsigned a0, unsigned a1) {
    return __builtin_amdgcn_perm(a1, a0, 0x07060302u);   // [a0>>16 | (a1>>16)<<16]
}

// ---------------------------------------------------------------- K0: ids + counts
__global__ __launch_bounds__(256) void k0_ids(
    const int* __restrict__ sem, const int* __restrict__ inst,
    uchar* __restrict__ id8, int* __restrict__ cnt)
{
    __shared__ int s_cnt[K];
    const int t = threadIdx.x;
    const int b = blockIdx.x / (NPTS / 2048);
    if (t < K) s_cnt[t] = 0;
    __syncthreads();

    const int base = blockIdx.x * 2048 + t * 8;
    const int4 c0 = *(const int4*)(sem + base);
    const int4 c1 = *(const int4*)(sem + base + 4);
    const int4 i0 = *(const int4*)(inst + base);
    const int4 i1 = *(const int4*)(inst + base + 4);
    const int cl[8] = {c0.x, c0.y, c0.z, c0.w, c1.x, c1.y, c1.z, c1.w};
    const int il[8] = {i0.x, i0.y, i0.z, i0.w, i1.x, i1.y, i1.z, i1.w};

    unsigned w0 = 0, w1 = 0;
#pragma unroll
    for (int j = 0; j < 8; ++j) {
        const bool v = (cl[j] != IGNORE_IDX);
        int q = (cl[j] == 1) ? 0 : il[j];
        q = (q < 0) ? 0 : (q > K - 1 ? K - 1 : q);
        if (v) atomicAdd(&s_cnt[q], 1);
        const unsigned byte = v ? (unsigned)q : 255u;
        if (j < 4) w0 |= byte << (8 * j);
        else       w1 |= byte << (8 * (j - 4));
    }
    *(uint2*)(id8 + base) = make_uint2(w0, w1);
    __syncthreads();

    if (t < K) {
        const int c = s_cnt[t];
        if (c) atomicAdd(&cnt[b * K + t], c);
    }
}

// ---------------------------------------------------------------- K1: segment sums via MFMA onehot
// C[d=32][khalf=32] += A(x)[d][n=16] * B(onehot)[n][khalf]
// A: m=lane&31, kdim=(lane>>5)*8+j.  B: ncol=lane&31, kdim same.
// C: col=lane&31, row=(reg&3)+8*(reg>>2)+4*(lane>>5)  [m74/m101 verified].
__global__ __launch_bounds__(256) void k1_mfma(
    const float* __restrict__ x, const uchar* __restrict__ id8,
    float* __restrict__ part)
{
    __shared__ float s_part[4][2048];
    const int t = threadIdx.x, w = t >> 6, L = t & 63;
    const int g = L >> 5, ln = L & 31;
    const unsigned lnu = (unsigned)ln, lnp32 = (unsigned)(ln + 32);
    const int blk = blockIdx.x, b = blk >> 7, sp = blk & (BPB - 1);

    const unsigned* xrow = (const unsigned*)(x + (size_t)b * D * NPTS
                                             + (size_t)ln * NPTS + sp * SPAN);
    const uchar* idb = id8 + (size_t)b * NPTS + sp * SPAN;

    f32x16 acc0, acc1;
#pragma unroll
    for (int i = 0; i < 16; ++i) { acc0[i] = 0.f; acc1[i] = 0.f; }

    for (int it = 0; it < SPAN / 64; ++it) {          // 16 iters, 16 pts/wave
        const int n0 = (it * 4 + w) * 16 + g * 8;
        const uint2 idq = *(const uint2*)(idb + n0);
        const uint4 xa = *(const uint4*)(xrow + n0);
        const uint4 xc = *(const uint4*)(xrow + n0 + 4);

        union { unsigned u[4]; bf16x8 v; } Ah, B0, B1;
        Ah.u[0] = bfpack(xa.x + 0x8000u, xa.y + 0x8000u);
        Ah.u[1] = bfpack(xa.z + 0x8000u, xa.w + 0x8000u);
        Ah.u[2] = bfpack(xc.x + 0x8000u, xc.y + 0x8000u);
        Ah.u[3] = bfpack(xc.z + 0x8000u, xc.w + 0x8000u);
#pragma unroll
        for (int p = 0; p < 4; ++p) {
            const unsigned pair = ((p < 2) ? idq.x : idq.y) >> ((p & 1) * 16);
            const unsigned e0 = pair & 255u, e1 = (pair >> 8) & 255u;
            unsigned r0 = (e0 == lnu)   ? 0x3F80u : 0u;
            unsigned r1 = (e0 == lnp32) ? 0x3F80u : 0u;
            if (e1 == lnu)   r0 |= 0x3F800000u;
            if (e1 == lnp32) r1 |= 0x3F800000u;
            B0.u[p] = r0; B1.u[p] = r1;
        }
        acc0 = __builtin_amdgcn_mfma_f32_32x32x16_bf16(Ah.v, B0.v, acc0, 0, 0, 0);
        acc1 = __builtin_amdgcn_mfma_f32_32x32x16_bf16(Ah.v, B1.v, acc1, 0, 0, 0);
    }

#pragma unroll
    for (int r = 0; r < 16; ++r) {
        const int row = (r & 3) + 8 * (r >> 2) + 4 * g;   // d
        s_part[w][row * 64 + ln]      = acc0[r];          // k = ln
        s_part[w][row * 64 + ln + 32] = acc1[r];          // k = ln+32
    }
    __syncthreads();

    float* dst = part + (size_t)blk * 2048;               // layout [d][k]
    for (int i = t; i < 2048; i += 256)
        dst[i] = s_part[0][i] + s_part[1][i] + s_part[2][i] + s_part[3][i];
}

// ---------------------------------------------------------------- K2: reduce -> mu[b][d][64]
__global__ __launch_bounds__(256) void k2_mu(const float* __restrict__ part,
                                             const int* __restrict__ cnt,
                                             float* __restrict__ mu)
{
    const int gid  = blockIdx.x * 256 + threadIdx.x;      // B*2048 = 16384
    const int b    = gid >> 11;
    const int cell = gid & 2047;                          // d*64 + k
    const int k    = cell & 63;
    float s = 0.f;
    for (int blk = 0; blk < BPB; ++blk)
        s += part[((size_t)(b * BPB + blk) << 11) + cell];
    mu[(size_t)b * 2048 + cell] = s / ((float)cnt[b * K + k] + 1e-8f);
}

// ---------------------------------------------------------------- K3: var via MFMA gather
// mu_pt[d][n] = mu[d][k] @ onehot[k][n]; dist = sum_d |x - mu_pt|; 1 scatter/pt
__global__ __launch_bounds__(256) void k3_mfma(
    const float* __restrict__ x, const uchar* __restrict__ id8,
    const float* __restrict__ mu, float* __restrict__ vpart)
{
    __shared__ float s_var[K];
    const int t = threadIdx.x, w = t >> 6, L = t & 63;
    const int g = L >> 5, ln = L & 31;
    const int blk = blockIdx.x, b = blk >> 7, sp = blk & (BPB - 1);
    if (t < K) s_var[t] = 0.f;

    // A-frags: mu[d=ln][k = c*16 + g*8 + j] (bf16 err ~1e-4 << budget)
    union { unsigned u[4]; bf16x8 v; } MAh[4];
    const unsigned* mrow = (const unsigned*)(mu + (size_t)b * 2048 + ln * 64);
#pragma unroll
    for (int c = 0; c < 4; ++c) {
        const uint4 m0 = *(const uint4*)(mrow + c * 16 + g * 8);
        const uint4 m1 = *(const uint4*)(mrow + c * 16 + g * 8 + 4);
        MAh[c].u[0] = bfpack(m0.x + 0x8000u, m0.y + 0x8000u);
        MAh[c].u[1] = bfpack(m0.z + 0x8000u, m0.w + 0x8000u);
        MAh[c].u[2] = bfpack(m1.x + 0x8000u, m1.y + 0x8000u);
        MAh[c].u[3] = bfpack(m1.z + 0x8000u, m1.w + 0x8000u);
    }
    __syncthreads();

    const float* xb  = x + (size_t)b * D * NPTS + sp * SPAN;
    const uchar* idb = id8 + (size_t)b * NPTS + sp * SPAN;

    for (int it = 0; it < SPAN / 128; ++it) {             // 8 iters, 32 pts/wave
        const int n0 = (it * 4 + w) * 32;
        const unsigned myid = idb[n0 + ln];
        // single-hot 8-bit mask for this lane's g-slice (zero if wrong g / invalid)
        const unsigned m8 = (myid < 64u && (((myid >> 3) & 1u) == (unsigned)g))
                          ? (1u << (myid & 7u)) : 0u;
        unsigned dw[4];
#pragma unroll
        for (int p = 0; p < 4; ++p) {
            const unsigned b0 = (m8 >> (2 * p)) & 1u;
            const unsigned b1 = (m8 >> (2 * p + 1)) & 1u;
            dw[p] = (b0 | (b1 << 16)) * 0x3F80u;
        }
        const unsigned cstar = myid >> 4;                 // >3 only when m8==0
        f32x16 acc;
#pragma unroll
        for (int i = 0; i < 16; ++i) acc[i] = 0.f;
#pragma unroll
        for (int c = 0; c < 4; ++c) {
            union { unsigned u[4]; bf16x8 v; } Bc;
#pragma unroll
            for (int p = 0; p < 4; ++p) Bc.u[p] = (cstar == (unsigned)c) ? dw[p] : 0u;
            acc = __builtin_amdgcn_mfma_f32_32x32x16_bf16(MAh[c].v, Bc.v, acc, 0, 0, 0);
        }
        float s = 0.f;
#pragma unroll
        for (int r = 0; r < 16; ++r) {
            const int row = (r & 3) + 8 * (r >> 2) + 4 * g;
            s += fabsf(xb[(size_t)row * NPTS + n0 + ln] - acc[r]);   // coalesced
        }
        s += __shfl_xor(s, 32, 64);                       // full 32-dim sum
        if (g == 0 && myid < 64u) {
            const float h = fmaxf(s - DELTA_V, 0.f);
            if (h > 0.f) unsafeAtomicAdd(&s_var[myid], h * h);
        }
    }
    __syncthreads();
    if (t < K) vpart[(size_t)blk * K + t] = s_var[t];
}

// ---------------------------------------------------------------- K4: finalize (8 blocks, one per batch)
__device__ float block_reduce_sum512(float v, float* s_buf) {
    for (int o = 32; o > 0; o >>= 1) v += __shfl_down(v, o, 64);
    const int wid  = threadIdx.x >> 6;
    const int lane = threadIdx.x & 63;
    if (lane == 0) s_buf[wid] = v;
    __syncthreads();
    float r = 0.f;
    if (threadIdx.x == 0)
        for (int w = 0; w < 8; ++w) r += s_buf[w];
    __syncthreads();
    return r;
}

__global__ __launch_bounds__(512) void k4_final(const float* __restrict__ mu,
                                                const int* __restrict__ cnt,
                                                const float* __restrict__ vpart,
                                                float* __restrict__ out)
{
    const int b = blockIdx.x;
    __shared__ float s_mu[K][D + 1];
    __shared__ float s_cnt[K];
    __shared__ float s_vp[8][K];
    __shared__ float s_red[8];

    const int t = threadIdx.x;
    if (t < K) s_cnt[t] = (float)cnt[b * K + t];

    {   // vpart partial reduce: pr=t>>6 owns chunks pr*16..+16 for k=t&63
        const int k = t & 63, pr = t >> 6;
        float vs = 0.f;
#pragma unroll
        for (int ch = pr * 16; ch < pr * 16 + 16; ++ch)
            vs += vpart[((size_t)(b * BPB + ch)) * K + k];
        s_vp[pr][k] = vs;
    }
    for (int i = t; i < K * D; i += 512)     // mu stored [d][k] -> s_mu[k][d]
        s_mu[i >> 5][i & 31] = mu[(size_t)b * 2048 + (i & 31) * 64 + (i >> 5)];
    __syncthreads();

    float distPart = 0.f;
    for (int p = t; p < K * K; p += 512) {
        const int i = p >> 6, j = p & 63;
        if (i != j && s_cnt[i] > 0.f && s_cnt[j] > 0.f) {
            float dsum = 0.f;
#pragma unroll
            for (int d = 0; d < D; ++d) dsum += fabsf(s_mu[i][d] - s_mu[j][d]);
            const float h = fmaxf(TWO_DELTA_D - dsum, 0.f);
            distPart += h * h;
        }
    }
    float regPart = 0.f;
    for (int i = t; i < K * D; i += 512) {
        const int k = i >> 5;
        if (s_cnt[k] > 0.f) regPart += fabsf(s_mu[k][i & 31]);
    }
    float varPart = 0.f, npPart = 0.f;
    if (t < K) {
        float vs = 0.f;
#pragma unroll
        for (int pr = 0; pr < 8; ++pr) vs += s_vp[pr][t];
        varPart = vs / (s_cnt[t] + 1e-8f);
        npPart  = (s_cnt[t] > 0.f) ? 1.f : 0.f;
    }

    const float distSum = block_reduce_sum512(distPart, s_red);
    const float regSum  = block_reduce_sum512(regPart,  s_red);
    const float varSum  = block_reduce_sum512(varPart,  s_red);
    const float npSum   = block_reduce_sum512(npPart,   s_red);

    if (t == 0) {
        const float n_inst = fmaxf(npSum, 1.0f);
        const float npairs = npSum * npSum - npSum;
        const float l_var  = varSum / n_inst;
        const float l_dist = (npairs > 0.f) ? (distSum / fmaxf(npairs, 1.0f)) : 0.f;
        const float l_reg  = PARAM_REG * (regSum / n_inst);
        const float invB   = 1.0f / (float)B;
        unsafeAtomicAdd(out + 0, (l_var + l_dist + l_reg) * invB);
        unsafeAtomicAdd(out + 1, l_var  * invB);
        unsafeAtomicAdd(out + 2, l_dist * invB);
        unsafeAtomicAdd(out + 3, l_reg  * invB);
    }
}

// ---------------------------------------------------------------- launch
extern "C" void kernel_launch(void* const* d_in, const int* in_sizes, int n_in,
                              void* d_out, int out_size, void* d_ws, size_t ws_size,
                              hipStream_t stream) {
    const float* x    = (const float*)d_in[0];
    const int*   sem  = (const int*)d_in[1];
    const int*   inst = (const int*)d_in[2];
    float*       out  = (float*)d_out;
    float*       ws   = (float*)d_ws;

    float* part  = ws;
    float* mu    = ws + OFF_MU;
    float* vpart = ws + OFF_VP;
    int*   cnt   = (int*)(ws + OFF_CNT);
    uchar* id8   = (uchar*)(ws + OFF_ID);

    hipMemsetAsync(cnt, 0, B * K * sizeof(int), stream);
    hipMemsetAsync(out, 0, (size_t)out_size * sizeof(float), stream);

    k0_ids<<<dim3(B * NPTS / 2048), dim3(256), 0, stream>>>(sem, inst, id8, cnt);
    k1_mfma<<<dim3(B * BPB), dim3(256), 0, stream>>>(x, id8, part);
    k2_mu<<<dim3(B * K * D / 256), dim3(256), 0, stream>>>(part, cnt, mu);
    k3_mfma<<<dim3(B * BPB), dim3(256), 0, stream>>>(x, id8, mu, vpart);
    k4_final<<<dim3(B), dim3(512), 0, stream>>>(mu, cnt, vpart, out);
}